// Round 10
// baseline (496.711 us; speedup 1.0000x reference)
//
#include <hip/hip_runtime.h>
#include <math.h>

#define NB 8
#define NN 1024
#define NK 8
#define ND 256
#define ND2 512
#define NBK 64
#define EPSA 1e-8f
#define LNEPS 1e-5f
#define GSTEP (2.0f/31.0f)

using short8 = __attribute__((ext_vector_type(8))) short;
using short4v = __attribute__((ext_vector_type(4))) short;
using floatx4 = __attribute__((ext_vector_type(4))) float;

__device__ __forceinline__ short f2bf(float f) {
  unsigned u = __builtin_bit_cast(unsigned, f);
  u += 0x7fffu + ((u >> 16) & 1u);
  return (short)(u >> 16);
}
__device__ __forceinline__ float bf2f(short s) {
  unsigned u = ((unsigned)(unsigned short)s) << 16;
  return __builtin_bit_cast(float, u);
}

// ---------------- weight conversions + bias folds + rank-2 vectors + scalars ----------------
__global__ __launch_bounds__(256) void k_cvt_all(
    const float* __restrict__ w1, const float* __restrict__ w2,
    const float* __restrict__ wk, const float* __restrict__ wv,
    const float* __restrict__ wih, const float* __restrict__ whh,
    const float* __restrict__ wq, const float* __restrict__ b2,
    const float* __restrict__ gpw, const float* __restrict__ lng,
    const float* __restrict__ lnb, const float* __restrict__ b1,
    short* __restrict__ w1T, short* __restrict__ wkT, short* __restrict__ wvT,
    short* __restrict__ whhp, short* __restrict__ w2B,
    float* __restrict__ bx, float* __restrict__ vb, float* __restrict__ vecs) {
  __shared__ float redS[4][32];
  const int blk = blockIdx.x;
  const int t = threadIdx.x;
  if (blk < 576) {
    const int id4 = blk * 256 + t;
    if (id4 < 32768) {
      const int i = id4 * 4;
      const int k = i >> 9, n0 = i & 511;
      const float4 v = *(const float4*)(w1 + (size_t)k * 512 + n0);
      const float vv[4] = {v.x, v.y, v.z, v.w};
#pragma unroll
      for (int q = 0; q < 4; q++) {
        const int n = n0 + q;
        const int dst = ((n >> 4) * 8 + (k >> 5)) * 512 + ((k >> 3) & 3) * 128 + (n & 15) * 8 + (k & 7);
        w1T[dst] = f2bf(vv[q]);
      }
    } else if (id4 < 49152) {
      const int i = (id4 - 32768) * 4;
      const int k = i >> 8, n0 = i & 255;
      const float4 v = *(const float4*)(wk + (size_t)k * 256 + n0);
      const float vv[4] = {v.x, v.y, v.z, v.w};
#pragma unroll
      for (int q = 0; q < 4; q++) {
        const int n = n0 + q;
        const int dst = ((n >> 4) * 8 + (k >> 5)) * 512 + ((k >> 3) & 3) * 128 + (n & 15) * 8 + (k & 7);
        wkT[dst] = f2bf(vv[q]);
      }
    } else if (id4 < 65536) {
      const int i = (id4 - 49152) * 4;
      const int k = i >> 8, n0 = i & 255;
      const float4 v = *(const float4*)(wv + (size_t)k * 256 + n0);
      const float vv[4] = {v.x, v.y, v.z, v.w};
#pragma unroll
      for (int q = 0; q < 4; q++) {
        const int n = n0 + q;
        const int dst = ((n >> 4) * 8 + (k >> 5)) * 512 + ((k >> 3) & 3) * 128 + (n & 15) * 8 + (k & 7);
        wvT[dst] = f2bf(vv[q]);
      }
    } else if (id4 < 114688) {
      const int i = (id4 - 65536) * 4;
      const int j = i >> 8, d0 = i & 255;
      const float4 v = *(const float4*)(whh + i);
      short4v pk = {f2bf(v.x), f2bf(v.y), f2bf(v.z), f2bf(v.w)};
      *(short4v*)&whhp[(size_t)((d0 >> 3) * 768 + j) * 8 + (d0 & 7)] = pk;
    } else {
      const int i = (id4 - 114688) * 4;
      const float4 v = *(const float4*)(w2 + i);
      short4v pk = {f2bf(v.x), f2bf(v.y), f2bf(v.z), f2bf(v.w)};
      *(short4v*)&w2B[i] = pk;
    }
  } else {
    const int fb = blk - 576;
    if (fb < 24) {
      const int o = t >> 3, sub = t & 7;
      const int j = fb * 32 + o;
      float p = 0.f;
#pragma unroll
      for (int q = 0; q < 8; q++) {
        const int d = sub * 32 + q * 4;
        const float4 wv4 = *(const float4*)(wih + (size_t)j * 256 + d);
        const float4 b4 = *(const float4*)(b2 + d);
        p += wv4.x * b4.x + wv4.y * b4.y + wv4.z * b4.z + wv4.w * b4.w;
      }
      p += __shfl_xor(p, 1); p += __shfl_xor(p, 2); p += __shfl_xor(p, 4);
      if (sub == 0) bx[j] = p;
    } else if (fb < 32) {
      const int o = t >> 3, sub = t & 7;
      const int e = (fb - 24) * 32 + o;
      float p = 0.f;
#pragma unroll
      for (int q = 0; q < 8; q++) {
        const int d = sub * 32 + q * 4;
        const float4 wv4 = *(const float4*)(wq + (size_t)e * 256 + d);
        const float4 b4 = *(const float4*)(b2 + d);
        p += wv4.x * b4.x + wv4.y * b4.y + wv4.z * b4.z + wv4.w * b4.w;
      }
      p += __shfl_xor(p, 1); p += __shfl_xor(p, 2); p += __shfl_xor(p, 4);
      if (sub == 0) vb[e] = p;
    } else if (fb < 96) {
      const int v = (fb - 32) >> 4;
      const int j0 = ((fb - 32) & 15) * 32;
      const int sub = t >> 5, o = t & 31;
      const int j = j0 + o;
      float p = 0.f;
#pragma unroll 8
      for (int q = 0; q < 32; q++) {
        const int d = sub * 32 + q;
        float c;
        if (v == 0) c = gpw[d] * lng[d];
        else if (v == 1) c = gpw[256 + d] * lng[d];
        else if (v == 2) c = lng[d];
        else c = lnb[d];
        p = fmaf(c, w1[(size_t)d * 512 + j], p);
      }
      p += __shfl_xor(p, 32);
      const int w = t >> 6;
      if ((t & 32) == 0) redS[w][o] = p;
      __syncthreads();
      if (t < 32) {
        float s = redS[0][t] + redS[1][t] + redS[2][t] + redS[3][t];
        if (v == 3) s += b1[j0 + t];
        vecs[v * 512 + j0 + t] = s;
      }
    } else {
      const float wa = gpw[t], wb = gpw[256 + t];
      float v0 = wa, v1 = wb, v2 = wa * wa, v3 = wb * wb, v4 = wa * wb;
#pragma unroll
      for (int m = 32; m >= 1; m >>= 1) {
        v0 += __shfl_xor(v0, m); v1 += __shfl_xor(v1, m); v2 += __shfl_xor(v2, m);
        v3 += __shfl_xor(v3, m); v4 += __shfl_xor(v4, m);
      }
      const int wv2 = t >> 6;
      if ((t & 63) == 0) {
        redS[wv2][0] = v0; redS[wv2][1] = v1; redS[wv2][2] = v2;
        redS[wv2][3] = v3; redS[wv2][4] = v4;
      }
      __syncthreads();
      if (t < 5)
        vecs[2048 + t] = (redS[0][t] + redS[1][t] + redS[2][t] + redS[3][t]) * (1.0f / 256.0f);
    }
  }
}

// ---------------- precompute WXTp/MQp (packed GEMV layouts) via MFMA ----------------
__global__ __launch_bounds__(256, 2) void k_mm(
    const float* __restrict__ wih, const float* __restrict__ wq,
    const short* __restrict__ w2B,
    short* __restrict__ WXTp, short* __restrict__ MQp) {
  const int z = blockIdx.z;
  if (z == 1 && blockIdx.x >= 4) return;
  const float* __restrict__ A = z ? wq : wih;
  __shared__ __align__(16) short As[64 * 264];
  const int row0 = blockIdx.x * 64;
  const int col0 = blockIdx.y * 128;
  const int t = threadIdx.x;
  const int wave = t >> 6, lane = t & 63, l15 = lane & 15, quad = lane >> 4;
  {
    const int r = t >> 2, sub = t & 3;
    const float* ar = A + (size_t)(row0 + r) * 256;
#pragma unroll
    for (int ii = 0; ii < 16; ii++) {
      const int d = sub * 4 + ii * 16;
      const float4 v = *(const float4*)(ar + d);
      short4v pk = {f2bf(v.x), f2bf(v.y), f2bf(v.z), f2bf(v.w)};
      *(short4v*)&As[r * 264 + d] = pk;
    }
  }
  __syncthreads();
  const short* wp = w2B + (size_t)(col0 + wave * 32 + l15) * 256 + quad * 8;
  floatx4 acc[4][2];
#pragma unroll
  for (int mt = 0; mt < 4; mt++)
#pragma unroll
    for (int nt = 0; nt < 2; nt++) acc[mt][nt] = (floatx4){0.f, 0.f, 0.f, 0.f};
#pragma unroll
  for (int kk = 0; kk < 8; kk++) {
    short8 af[4];
#pragma unroll
    for (int mt = 0; mt < 4; mt++)
      af[mt] = *(const short8*)&As[(mt * 16 + l15) * 264 + kk * 32 + quad * 8];
    short8 bf[2];
#pragma unroll
    for (int nt = 0; nt < 2; nt++)
      bf[nt] = *(const short8*)(wp + nt * 16 * 256 + kk * 32);
#pragma unroll
    for (int mt = 0; mt < 4; mt++)
#pragma unroll
      for (int nt = 0; nt < 2; nt++)
        acc[mt][nt] = __builtin_amdgcn_mfma_f32_16x16x32_bf16(af[mt], bf[nt], acc[mt][nt], 0, 0, 0);
  }
#pragma unroll
  for (int mt = 0; mt < 4; mt++)
#pragma unroll
    for (int nt = 0; nt < 2; nt++)
#pragma unroll
      for (int j = 0; j < 4; j++) {
        const int row = row0 + mt * 16 + quad * 4 + j;
        const int col = col0 + wave * 32 + nt * 16 + l15;
        const short val = f2bf(acc[mt][nt][j]);
        if (z) MQp[(size_t)((row >> 3) * 512 + col) * 8 + (row & 7)] = val;
        else   WXTp[(size_t)((col >> 3) * 768 + row) * 8 + (col & 7)] = val;
      }
}

// ---------------- k_kv_kw: fused LN->kv MFMA->(+gpb)*g + moments -> @W1 MFMA -> KW ----------------
__global__ __launch_bounds__(256, 2) void k_kv_kw(
    const float* __restrict__ inp,
    const float* __restrict__ nig, const float* __restrict__ nib,
    const short* __restrict__ wkT, const short* __restrict__ wvT,
    const float* __restrict__ gpb, const float* __restrict__ gpw,
    const float* __restrict__ lng,
    const short* __restrict__ w1T,
    short* __restrict__ KWk, short* __restrict__ KWv,
    float* __restrict__ momk, float* __restrict__ momv) {
  __shared__ __align__(16) short tln[64 * 264];
  __shared__ float momS[64][4][4];
  const short* __restrict__ WT = blockIdx.z ? wvT : wkT;
  short* __restrict__ KW = blockIdx.z ? KWv : KWk;
  float* __restrict__ mom = blockIdx.z ? momv : momk;
  const int row0 = blockIdx.x * 64;
  const int t = threadIdx.x;
  const int wave = t >> 6, lane = t & 63, l15 = lane & 15, quad = lane >> 4;
  {
    const int r = t >> 2, sub = t & 3;
    const float* xr = inp + (size_t)(row0 + r) * ND;
    float tv[64];
    float sum = 0.f, ssq = 0.f;
#pragma unroll
    for (int ii = 0; ii < 16; ii++) {
      const int d = sub * 4 + ii * 16;
      const float4 xv = *(const float4*)(xr + d);
      tv[ii * 4 + 0] = xv.x; sum += xv.x; ssq += xv.x * xv.x;
      tv[ii * 4 + 1] = xv.y; sum += xv.y; ssq += xv.y * xv.y;
      tv[ii * 4 + 2] = xv.z; sum += xv.z; ssq += xv.z * xv.z;
      tv[ii * 4 + 3] = xv.w; sum += xv.w; ssq += xv.w * xv.w;
    }
    sum += __shfl_xor(sum, 1); ssq += __shfl_xor(ssq, 1);
    sum += __shfl_xor(sum, 2); ssq += __shfl_xor(ssq, 2);
    const float mean = sum * (1.0f / ND);
    const float var = ssq * (1.0f / ND) - mean * mean;
    const float rstd = rsqrtf(var + LNEPS);
#pragma unroll
    for (int ii = 0; ii < 16; ii++) {
      const int d = sub * 4 + ii * 16;
      const float4 gg = *(const float4*)(nig + d);
      const float4 bb = *(const float4*)(nib + d);
      short4v pk;
      pk.x = f2bf((tv[ii * 4 + 0] - mean) * rstd * gg.x + bb.x);
      pk.y = f2bf((tv[ii * 4 + 1] - mean) * rstd * gg.y + bb.y);
      pk.z = f2bf((tv[ii * 4 + 2] - mean) * rstd * gg.z + bb.z);
      pk.w = f2bf((tv[ii * 4 + 3] - mean) * rstd * gg.w + bb.w);
      *(short4v*)&tln[r * 264 + d] = pk;
    }
  }
  __syncthreads();
  floatx4 acc[4][4];
#pragma unroll
  for (int mt = 0; mt < 4; mt++)
#pragma unroll
    for (int nt = 0; nt < 4; nt++) acc[mt][nt] = (floatx4){0.f, 0.f, 0.f, 0.f};
  {
    const short* wp = WT + (size_t)(wave * 32) * 512 + (size_t)lane * 8;
#pragma unroll
    for (int kk = 0; kk < 8; kk++) {
      short8 af[4];
#pragma unroll
      for (int mt = 0; mt < 4; mt++)
        af[mt] = *(const short8*)&tln[(mt * 16 + l15) * 264 + kk * 32 + quad * 8];
      short8 bf[4];
#pragma unroll
      for (int nt = 0; nt < 4; nt++)
        bf[nt] = *(const short8*)(wp + (nt * 8 + kk) * 512);
#pragma unroll
      for (int mt = 0; mt < 4; mt++)
#pragma unroll
        for (int nt = 0; nt < 4; nt++)
          acc[mt][nt] = __builtin_amdgcn_mfma_f32_16x16x32_bf16(af[mt], bf[nt], acc[mt][nt], 0, 0, 0);
    }
  }
  __syncthreads();
  {
    float waL[4], wbL[4], ggL[4], pbL[4];
#pragma unroll
    for (int nt = 0; nt < 4; nt++) {
      const int c = wave * 64 + nt * 16 + l15;
      waL[nt] = gpw[c]; wbL[nt] = gpw[256 + c];
      ggL[nt] = lng[c]; pbL[nt] = gpb[c];
    }
#pragma unroll
    for (int mt = 0; mt < 4; mt++)
#pragma unroll
      for (int j = 0; j < 4; j++) {
        const int row = mt * 16 + quad * 4 + j;
        float su = 0.f, sq = 0.f, sa = 0.f, sb = 0.f;
#pragma unroll
        for (int nt = 0; nt < 4; nt++) {
          const float u = acc[mt][nt][j] + pbL[nt];
          su += u; sq += u * u; sa += u * waL[nt]; sb += u * wbL[nt];
          tln[row * 264 + wave * 64 + nt * 16 + l15] = f2bf(u * ggL[nt]);
        }
        su += __shfl_xor(su, 1); sq += __shfl_xor(sq, 1);
        sa += __shfl_xor(sa, 1); sb += __shfl_xor(sb, 1);
        su += __shfl_xor(su, 2); sq += __shfl_xor(sq, 2);
        sa += __shfl_xor(sa, 2); sb += __shfl_xor(sb, 2);
        su += __shfl_xor(su, 4); sq += __shfl_xor(sq, 4);
        sa += __shfl_xor(sa, 4); sb += __shfl_xor(sb, 4);
        su += __shfl_xor(su, 8); sq += __shfl_xor(sq, 8);
        sa += __shfl_xor(sa, 8); sb += __shfl_xor(sb, 8);
        if (l15 == 0) {
          momS[row][wave][0] = su; momS[row][wave][1] = sq;
          momS[row][wave][2] = sa; momS[row][wave][3] = sb;
        }
      }
  }
  __syncthreads();
  if (t < 64) {
    const float m0 = momS[t][0][0] + momS[t][1][0] + momS[t][2][0] + momS[t][3][0];
    const float m1 = momS[t][0][1] + momS[t][1][1] + momS[t][2][1] + momS[t][3][1];
    const float m2 = momS[t][0][2] + momS[t][1][2] + momS[t][2][2] + momS[t][3][2];
    const float m3 = momS[t][0][3] + momS[t][1][3] + momS[t][2][3] + momS[t][3][3];
    float* mp = mom + (size_t)(row0 + t) * 4;
    mp[0] = m0 * (1.0f / ND); mp[1] = m1 * (1.0f / ND);
    mp[2] = m2 * (1.0f / ND); mp[3] = m3 * (1.0f / ND);
  }
  floatx4 acc2[4][8];
#pragma unroll
  for (int mt = 0; mt < 4; mt++)
#pragma unroll
    for (int nt = 0; nt < 8; nt++) acc2[mt][nt] = (floatx4){0.f, 0.f, 0.f, 0.f};
  const short* w1p = w1T + (size_t)(wave * 64) * 512 + (size_t)lane * 8;
#pragma unroll
  for (int kk = 0; kk < 8; kk++) {
    short8 af[4];
#pragma unroll
    for (int mt = 0; mt < 4; mt++)
      af[mt] = *(const short8*)&tln[(mt * 16 + l15) * 264 + kk * 32 + quad * 8];
    short8 bf[8];
#pragma unroll
    for (int nt = 0; nt < 8; nt++)
      bf[nt] = *(const short8*)(w1p + (nt * 8 + kk) * 512);
#pragma unroll
    for (int mt = 0; mt < 4; mt++)
#pragma unroll
      for (int nt = 0; nt < 8; nt++)
        acc2[mt][nt] = __builtin_amdgcn_mfma_f32_16x16x32_bf16(af[mt], bf[nt], acc2[mt][nt], 0, 0, 0);
  }
#pragma unroll
  for (int mt = 0; mt < 4; mt++)
#pragma unroll
    for (int nt = 0; nt < 8; nt++)
#pragma unroll
      for (int j = 0; j < 4; j++)
        KW[(size_t)(row0 + mt * 16 + quad * 4 + j) * 512 + wave * 128 + nt * 16 + l15] =
            f2bf(acc2[mt][nt][j]);
}

// ---------------- k_iter: fused dots(8 slots) + softmax + moments + ph ----------------
// grid (64, NB): 16 rows per block (wave handles 4), all 8 slots. 64 ph-partials + stage moments.
__global__ __launch_bounds__(256) void k_iter(
    const short* __restrict__ KWk, const short* __restrict__ KWv,
    const float* __restrict__ momk, const float* __restrict__ momv,
    const float* __restrict__ vecs,
    const float* __restrict__ pos, const float* __restrict__ scl,
    const float* __restrict__ w2q, float* __restrict__ stage,
    float* __restrict__ php) {
  const int b = blockIdx.y, nt = blockIdx.x;
  const int t = threadIdx.x, wave = t >> 6, lane = t & 63;
  __shared__ float w2qS[8 * 512];   // w2q for 8 slots; aliased as phs after row loop
  __shared__ float momRed[4][40];
#pragma unroll
  for (int q = 0; q < 16; q++)
    w2qS[q * 256 + t] = w2q[(size_t)b * 4096 + q * 256 + t];
  __syncthreads();
  float AWv[8], BWv[8], GWv[8], bWv[8];
#pragma unroll
  for (int e = 0; e < 8; e++) {
    const int j = e * 64 + lane;
    AWv[e] = vecs[j]; BWv[e] = vecs[512 + j];
    GWv[e] = vecs[1024 + j]; bWv[e] = vecs[1536 + j];
  }
  const float mwa = vecs[2048], mwb = vecs[2049];
  const float ewa2 = vecs[2050], ewb2 = vecs[2051], ewab = vecs[2052];
  float p0[8], p1[8], si0[8], si1[8], qb2[8];
#pragma unroll
  for (int k = 0; k < 8; k++) {
    const int bk = b * 8 + k;
    p0[k] = pos[bk * 2]; p1[k] = pos[bk * 2 + 1];
    si0[k] = 1.0f / (scl[bk * 2] * 5.0f);
    si1[k] = 1.0f / (scl[bk * 2 + 1] * 5.0f);
    qb2[k] = stage[bk * 8 + 5];
  }
  float acc[8][8];
#pragma unroll
  for (int k = 0; k < 8; k++)
#pragma unroll
    for (int e = 0; e < 8; e++) acc[k][e] = 0.f;
  float msum = 0.f;
  const int mk = lane / 5, mc = lane - mk * 5;  // lane<40: owns moment (mk, mc)
#pragma unroll
  for (int i = 0; i < 4; i++) {
    const int n = nt * 16 + wave * 4 + i;
    const int row = b * NN + n;
    const float gx = -1.0f + GSTEP * (float)(n >> 5);
    const float gy = -1.0f + GSTEP * (float)(n & 31);
    // ---- dots phase (KWk, momk) ----
    float KWr[8];
#pragma unroll
    for (int e = 0; e < 8; e++) KWr[e] = bf2f(KWk[(size_t)row * 512 + e * 64 + lane]);
    {
      const float mu = momk[row * 4 + 0], qm = momk[row * 4 + 1];
      const float ca = momk[row * 4 + 2], cb = momk[row * 4 + 3];
      float dk[8];
#pragma unroll
      for (int k = 0; k < 8; k++) {
        const float rg0 = (gx - p0[k]) * si0[k];
        const float rg1 = (gy - p1[k]) * si1[k];
        const float mean = mu + rg0 * mwa + rg1 * mwb;
        const float ey2 = qm + rg0 * rg0 * ewa2 + rg1 * rg1 * ewb2 +
                          2.0f * (rg0 * ca + rg1 * cb + rg0 * rg1 * ewab);
        const float rstd = rsqrtf(ey2 - mean * mean + LNEPS);
        float d = 0.f;
#pragma unroll
        for (int e = 0; e < 8; e++) {
          float tt = KWr[e];
          tt = fmaf(rg0, AWv[e], tt);
          tt = fmaf(rg1, BWv[e], tt);
          tt = fmaf(-mean, GWv[e], tt);
          const float h = fmaf(rstd, tt, bWv[e]);
          d = fmaf(fmaxf(h, 0.f), w2qS[k * 512 + e * 64 + lane], d);
        }
        d += __shfl_xor(d, 1); d += __shfl_xor(d, 2); d += __shfl_xor(d, 4);
        d += __shfl_xor(d, 8); d += __shfl_xor(d, 16); d += __shfl_xor(d, 32);
        dk[k] = (d + qb2[k]) * 0.0625f;
      }
      // ---- softmax (all lanes redundantly) ----
      float mx = dk[0];
#pragma unroll
      for (int k = 1; k < 8; k++) mx = fmaxf(mx, dk[k]);
      float s = 0.f;
#pragma unroll
      for (int k = 0; k < 8; k++) { dk[k] = expf(dk[k] - mx); s += dk[k]; }
      const float inv = 1.0f / s;
#pragma unroll
      for (int k = 0; k < 8; k++) dk[k] *= inv;   // dk now = attn
      // ---- moments (lane<40: one (k,c) each) ----
      if (lane < 40) {
        const float a = dk[mk];
        float mval;
        if (mc == 0) mval = a;
        else if (mc == 1) mval = a * gx;
        else if (mc == 2) mval = a * gy;
        else if (mc == 3) mval = (a + EPSA) * gx * gx;
        else mval = (a + EPSA) * gy * gy;
        msum += mval;
      }
      // ---- ph phase (KWv, momv) ----
#pragma unroll
      for (int e = 0; e < 8; e++) KWr[e] = bf2f(KWv[(size_t)row * 512 + e * 64 + lane]);
      const float mu2 = momv[row * 4 + 0], qm2 = momv[row * 4 + 1];
      const float ca2 = momv[row * 4 + 2], cb2 = momv[row * 4 + 3];
#pragma unroll
      for (int k = 0; k < 8; k++) {
        const float rg0 = (gx - p0[k]) * si0[k];
        const float rg1 = (gy - p1[k]) * si1[k];
        const float mean = mu2 + rg0 * mwa + rg1 * mwb;
        const float ey2 = qm2 + rg0 * rg0 * ewa2 + rg1 * rg1 * ewb2 +
                          2.0f * (rg0 * ca2 + rg1 * cb2 + rg0 * rg1 * ewab);
        const float rstd = rsqrtf(ey2 - mean * mean + LNEPS);
        const float aw = dk[k] + EPSA;
#pragma unroll
        for (int e = 0; e < 8; e++) {
          float tt = KWr[e];
          tt = fmaf(rg0, AWv[e], tt);
          tt = fmaf(rg1, BWv[e], tt);
          tt = fmaf(-mean, GWv[e], tt);
          const float h = fmaf(rstd, tt, bWv[e]);
          acc[k][e] = fmaf(aw, fmaxf(h, 0.f), acc[k][e]);
        }
      }
    }
  }
  // ---- moments: cross-wave reduce + atomic ----
  if (lane < 40) momRed[wave][lane] = msum;
  __syncthreads();   // also guarantees all w2qS reads complete
  if (t < 40) {
    const float tot = momRed[0][t] + momRed[1][t] + momRed[2][t] + momRed[3][t];
    atomicAdd(&stage[(b * 8 + t / 5) * 8 + (t % 5)], tot);
  }
  // ---- cross-wave combine acc into phs (alias w2qS) ----
  float* phs = w2qS;
#pragma unroll
  for (int w = 0; w < 4; w++) {
    if (wave == w) {
#pragma unroll
      for (int k = 0; k < 8; k++)
#pragma unroll
        for (int e = 0; e < 8; e++) {
          const int j = k * 512 + e * 64 + lane;
          if (w == 0) phs[j] = acc[k][e];
          else phs[j] += acc[k][e];
        }
    }
    __syncthreads();
  }
  float* dst = php + (size_t)((nt * 8 + b) * 8) * 512;
  const int base = t * 16;
#pragma unroll
  for (int q = 0; q < 4; q++)
    *(float4*)(dst + base + q * 4) = *(const float4*)(phs + base + q * 4);
}

// ---------------- k_dots: final-iteration dots (z-split) ----------------
__global__ __launch_bounds__(256) void k_dots(
    const short* __restrict__ KW, const float* __restrict__ mom,
    const float* __restrict__ vecs,
    const float* __restrict__ pos, const float* __restrict__ scl,
    const float* __restrict__ w2q, const float* __restrict__ stage,
    float* __restrict__ dots) {
  const int b = blockIdx.y, nt = blockIdx.x, kk0 = blockIdx.z * 4;
  const int t = threadIdx.x, wave = t >> 6, lane = t & 63;
  float AWv[8], BWv[8], GWv[8], bWv[8];
#pragma unroll
  for (int e = 0; e < 8; e++) {
    const int j = e * 64 + lane;
    AWv[e] = vecs[j]; BWv[e] = vecs[512 + j];
    GWv[e] = vecs[1024 + j]; bWv[e] = vecs[1536 + j];
  }
  const float mwa = vecs[2048], mwb = vecs[2049];
  const float ewa2 = vecs[2050], ewb2 = vecs[2051], ewab = vecs[2052];
  float p0[4], p1[4], si0[4], si1[4], qb2[4];
#pragma unroll
  for (int k = 0; k < 4; k++) {
    const int bk = b * 8 + kk0 + k;
    p0[k] = pos[bk * 2]; p1[k] = pos[bk * 2 + 1];
    si0[k] = 1.0f / (scl[bk * 2] * 5.0f);
    si1[k] = 1.0f / (scl[bk * 2 + 1] * 5.0f);
    qb2[k] = stage[bk * 8 + 5];
  }
#pragma unroll
  for (int i = 0; i < 2; i++) {
    const int n = nt * 8 + wave * 2 + i;
    const int row = b * NN + n;
    float KWr[8];
#pragma unroll
    for (int e = 0; e < 8; e++) KWr[e] = bf2f(KW[(size_t)row * 512 + e * 64 + lane]);
    const float mu = mom[row * 4 + 0], qm = mom[row * 4 + 1];
    const float ca = mom[row * 4 + 2], cb = mom[row * 4 + 3];
    const float gx = -1.0f + GSTEP * (float)(n >> 5);
    const float gy = -1.0f + GSTEP * (float)(n & 31);
#pragma unroll
    for (int k = 0; k < 4; k++) {
      const float rg0 = (gx - p0[k]) * si0[k];
      const float rg1 = (gy - p1[k]) * si1[k];
      const float mean = mu + rg0 * mwa + rg1 * mwb;
      const float ey2 = qm + rg0 * rg0 * ewa2 + rg1 * rg1 * ewb2 +
                        2.0f * (rg0 * ca + rg1 * cb + rg0 * rg1 * ewab);
      const float rstd = rsqrtf(ey2 - mean * mean + LNEPS);
      const float* wq = w2q + (size_t)(b * 8 + kk0 + k) * 512;
      float d = 0.f;
#pragma unroll
      for (int e = 0; e < 8; e++) {
        float tt = KWr[e];
        tt = fmaf(rg0, AWv[e], tt);
        tt = fmaf(rg1, BWv[e], tt);
        tt = fmaf(-mean, GWv[e], tt);
        const float h = fmaf(rstd, tt, bWv[e]);
        d = fmaf(fmaxf(h, 0.f), wq[e * 64 + lane], d);
      }
      d += __shfl_xor(d, 1); d += __shfl_xor(d, 2); d += __shfl_xor(d, 4);
      d += __shfl_xor(d, 8); d += __shfl_xor(d, 16); d += __shfl_xor(d, 32);
      if (lane == 0) dots[(size_t)(b * 8 + kk0 + k) * NN + n] = (d + qb2[k]) * 0.0625f;
    }
  }
}

// ---------------- softmax over K + one-pass moment sums -> stage (final iteration) ----------------
__global__ __launch_bounds__(64) void k_softmax_reduce(
    const float* __restrict__ dots, float* __restrict__ attn0,
    float* __restrict__ stage) {
  const int t = threadIdx.x;
  const int idx = blockIdx.x * 64 + t;
  const int b = idx >> 10, n = idx & 1023;
  float vals[NK];
  float mx = -1e30f;
#pragma unroll
  for (int k = 0; k < NK; k++) {
    vals[k] = dots[(size_t)(b * NK + k) * NN + n];
    mx = fmaxf(mx, vals[k]);
  }
  float s = 0.f;
#pragma unroll
  for (int k = 0; k < NK; k++) { vals[k] = expf(vals[k] - mx); s += vals[k]; }
  const float inv = 1.0f / s;
  const float gx = -1.0f + GSTEP * (float)(n >> 5);
  const float gy = -1.0f + GSTEP * (float)(n & 31);
  const float gx2 = gx * gx, gy2 = gy * gy;
  float sk[NK][5];
#pragma unroll
  for (int k = 0; k < NK; k++) {
    const float a = vals[k] * inv;
    attn0[(size_t)(b * NK + k) * NN + n] = a;
    const float w = a + EPSA;
    sk[k][0] = a;
    sk[k][1] = a * gx;
    sk[k][2] = a * gy;
    sk[k][3] = w * gx2;
    sk[k][4] = w * gy2;
  }
#pragma unroll
  for (int m = 32; m >= 1; m >>= 1)
#pragma unroll
    for (int k = 0; k < NK; k++)
#pragma unroll
      for (int c = 0; c < 5; c++)
        sk[k][c] += __shfl_xor(sk[k][c], m);
  __shared__ float red[40];
  if (t == 0) {
#pragma unroll
    for (int k = 0; k < NK; k++)
#pragma unroll
      for (int c = 0; c < 5; c++)
        red[k * 5 + c] = sk[k][c];
  }
  __syncthreads();
  if (t < 40) {
    const int k = t / 5, c = t % 5;
    atomicAdd(&stage[(b * NK + k) * 8 + c], red[t]);
  }
}

// ---------------- k_tail: phred(64 partials) + gates GEMV + GRU + LN + w2q + qb2 ----------------
__global__ __launch_bounds__(256) void k_tail(
    const float* __restrict__ php, float* __restrict__ sf,
    const short* __restrict__ WXTp, const short* __restrict__ whhp,
    const float* __restrict__ bx,
    const float* __restrict__ bih, const float* __restrict__ bhh,
    const float* __restrict__ nsg, const float* __restrict__ nsb,
    const short* __restrict__ MQp, const float* __restrict__ vb,
    float* __restrict__ w2q, float* __restrict__ pos, float* __restrict__ scl,
    float* __restrict__ stage) {
  const int bk = blockIdx.x, t = threadIdx.x;
  const int b = bk >> 3, k = bk & 7;
  __shared__ float phv[512];
  __shared__ float sfv[256];
  __shared__ float lnvS[256];
  __shared__ float red[8];
  const int wv = t >> 6;
  sfv[t] = sf[bk * 260 + t];
  const float dn = 1.0f / (stage[bk * 8 + 0] + (float)NN * EPSA);
  float s0 = 0.f, s1 = 0.f;
#pragma unroll 8
  for (int p = 0; p < 64; p++) {
    const float* src = php + (size_t)((p * 8 + b) * 8 + k) * 512;
    s0 += src[t];
    s1 += src[t + 256];
  }
  phv[t] = s0 * dn;
  phv[t + 256] = s1 * dn;
  __syncthreads();
  float x0 = bx[t], x1 = bx[256 + t], x2 = bx[512 + t];
#pragma unroll 4
  for (int e8 = 0; e8 < 64; e8++) {
    const float4 pa = *(const float4*)&phv[e8 * 8];
    const float4 pb4 = *(const float4*)&phv[e8 * 8 + 4];
    const float pv[8] = {pa.x, pa.y, pa.z, pa.w, pb4.x, pb4.y, pb4.z, pb4.w};
    const short8 wr0 = *(const short8*)&WXTp[(size_t)(e8 * 768 + t) * 8];
    const short8 wr1 = *(const short8*)&WXTp[(size_t)(e8 * 768 + 256 + t) * 8];
    const short8 wr2 = *(const short8*)&WXTp[(size_t)(e8 * 768 + 512 + t) * 8];
#pragma unroll
    for (int r = 0; r < 8; r++) {
      x0 = fmaf(pv[r], bf2f(wr0[r]), x0);
      x1 = fmaf(pv[r], bf2f(wr1[r]), x1);
      x2 = fmaf(pv[r], bf2f(wr2[r]), x2);
    }
  }
  float h0 = 0.f, h1v = 0.f, h2 = 0.f;
#pragma unroll 4
  for (int d8 = 0; d8 < 32; d8++) {
    const float4 sa = *(const float4*)&sfv[d8 * 8];
    const float4 sb4 = *(const float4*)&sfv[d8 * 8 + 4];
    const float sv[8] = {sa.x, sa.y, sa.z, sa.w, sb4.x, sb4.y, sb4.z, sb4.w};
    const short8 hr0 = *(const short8*)&whhp[(size_t)(d8 * 768 + t) * 8];
    const short8 hr1 = *(const short8*)&whhp[(size_t)(d8 * 768 + 256 + t) * 8];
    const short8 hr2 = *(const short8*)&whhp[(size_t)(d8 * 768 + 512 + t) * 8];
#pragma unroll
    for (int r = 0; r < 8; r++) {
      h0 = fmaf(sv[r], bf2f(hr0[r]), h0);
      h1v = fmaf(sv[r], bf2f(hr1[r]), h1v);
      h2 = fmaf(sv[r], bf2f(hr2[r]), h2);
    }
  }
  const float r = 1.0f / (1.0f + expf(-(x0 + bih[t] + h0 + bhh[t])));
  const float z = 1.0f / (1.0f + expf(-(x1 + bih[256 + t] + h1v + bhh[256 + t])));
  const float nw = tanhf(x2 + bih[512 + t] + r * (h2 + bhh[512 + t]));
  const float ns = (1.0f - z) * nw + z * sfv[t];
  sf[bk * 260 + t] = ns;
  float s2 = ns, ss = ns * ns;
#pragma unroll
  for (int m = 32; m >= 1; m >>= 1) { s2 += __shfl_xor(s2, m); ss += __shfl_xor(ss, m); }
  if ((t & 63) == 0) { red[wv] = s2; red[4 + wv] = ss; }
  __syncthreads();
  const float S = red[0] + red[1] + red[2] + red[3];
  const float SS = red[4] + red[5] + red[6] + red[7];
  const float mean = S * (1.0f / ND);
  const float var = SS * (1.0f / ND) - mean * mean;
  const float rstd = rsqrtf(var + LNEPS);
  const float lnv = (ns - mean) * rstd * nsg[t] + nsb[t];
  lnvS[t] = lnv;
  if (t == 0) {
    const float Sa = stage[bk * 8 + 0];
    const float G0 = stage[bk * 8 + 1];
    const float G1 = stage[bk * 8 + 2];
    const float Q0 = stage[bk * 8 + 3];
    const float Q1 = stage[bk * 8 + 4];
    const float W = Sa + (float)NN * EPSA;
    const float sc0 = sqrtf(fmaxf(Q0 - 2.0f * G0 * G0 + G0 * G0 * W, 0.f));
    const float sc1 = sqrtf(fmaxf(Q1 - 2.0f * G1 * G1 + G1 * G1 * W, 0.f));
    const float sc0c = fminf(fmaxf(sc0, 1e-3f), 2.0f);
    const float sc1c = fminf(fmaxf(sc1, 1e-3f), 2.0f);
    sf[bk * 260 + 256] = G0;
    sf[bk * 260 + 257] = G1;
    sf[bk * 260 + 258] = sc0c;
    sf[bk * 260 + 259] = sc1c;
    pos[bk * 2 + 0] = fminf(fmaxf(G0, -1.0f), 1.0f);
    pos[bk * 2 + 1] = fminf(fmaxf(G1, -1.0f), 1.0f);
    scl[bk * 2 + 0] = sc0c;
    scl[bk * 2 + 1] = sc1c;
  }
  __syncthreads();
  if (t < 5) stage[bk * 8 + t] = 0.f;
  float w0 = 0.f, w1v = 0.f;
#pragma unroll 4
  for (int e8 = 0; e8 < 32; e8++) {
    const float4 la = *(const float4*)&lnvS[e8 * 8];
    const float4 lb = *(const float4*)&lnvS[e8 * 8 + 4];
    const float lv[8] = {la.x, la.y, la.z, la.w, lb.x, lb.y, lb.z, lb.w};
    const short8 m0 = *(const short8*)&MQp[(size_t)(e8 * 512 + t) * 8];
    const short8 m1 = *(const short8*)&MQp[(size_t)(e8 * 512 + 256 + t) * 8];
#pragma unroll
    for (int rr = 0; rr < 8; rr++) {
      w0 = fmaf(lv[rr], bf2f(m0[rr]), w0);
      w1v = fmaf(lv[rr], bf2f(m1[rr]), w1v);
    }
  }
  w2q[bk * 512 + t] = w0;
  w2q[bk * 512 + 256 + t] = w1v;
  float qd = lnvS[t] * vb[t];
#pragma unroll
  for (int m = 32; m >= 1; m >>= 1) qd += __shfl_xor(qd, m);
  __syncthreads();
  if ((t & 63) == 0) red[wv] = qd;
  __syncthreads();
  if (t == 0) stage[bk * 8 + 5] = red[0] + red[1] + red[2] + red[3];
}

// ---------------- k_slot0: iteration-0 slot init (no GRU) ----------------
__global__ __launch_bounds__(256) void k_slot0(
    float* __restrict__ sf, const float* __restrict__ cond,
    const float* __restrict__ nsg, const float* __restrict__ nsb,
    const short* __restrict__ MQp, const float* __restrict__ vb,
    float* __restrict__ w2q, float* __restrict__ pos, float* __restrict__ scl,
    float* __restrict__ stage) {
  const int bk = blockIdx.x, t = threadIdx.x;
  __shared__ float lnvS[256];
  __shared__ float red[8];
  const int wv = t >> 6;
  const float ns = cond[bk * 260 + t];
  sf[bk * 260 + t] = ns;
  if (t < 4) sf[bk * 260 + 256 + t] = cond[bk * 260 + 256 + t];
  float s2 = ns, ss = ns * ns;
#pragma unroll
  for (int m = 32; m >= 1; m >>= 1) { s2 += __shfl_xor(s2, m); ss += __shfl_xor(ss, m); }
  if ((t & 63) == 0) { red[wv] = s2; red[4 + wv] = ss; }
  __syncthreads();
  const float S = red[0] + red[1] + red[2] + red[3];
  const float SS = red[4] + red[5] + red[6] + red[7];
  const float mean = S * (1.0f / ND);
  const float var = SS * (1.0f / ND) - mean * mean;
  const float rstd = rsqrtf(var + LNEPS);
  const float lnv = (ns - mean) * rstd * nsg[t] + nsb[t];
  lnvS[t] = lnv;
  if (t < 2) {
    const float p = cond[bk * 260 + 256 + t];
    pos[bk * 2 + t] = fminf(fmaxf(p, -1.0f), 1.0f);
    const float sc = cond[bk * 260 + 258 + t];
    scl[bk * 2 + t] = fminf(fmaxf(sc, 1e-3f), 2.0f);
  }
  __syncthreads();
  if (t < 5) stage[bk * 8 + t] = 0.f;
  float w0 = 0.f, w1v = 0.f;
#pragma unroll 4
  for (int e8 = 0; e8 < 32; e8++) {
    const float4 la = *(const float4*)&lnvS[e8 * 8];
    const float4 lb = *(const float4*)&lnvS[e8 * 8 + 4];
    const float lv[8] = {la.x, la.y, la.z, la.w, lb.x, lb.y, lb.z, lb.w};
    const short8 m0 = *(const short8*)&MQp[(size_t)(e8 * 512 + t) * 8];
    const short8 m1 = *(const short8*)&MQp[(size_t)(e8 * 512 + 256 + t) * 8];
#pragma unroll
    for (int rr = 0; rr < 8; rr++) {
      w0 = fmaf(lv[rr], bf2f(m0[rr]), w0);
      w1v = fmaf(lv[rr], bf2f(m1[rr]), w1v);
    }
  }
  w2q[bk * 512 + t] = w0;
  w2q[bk * 512 + 256 + t] = w1v;
  float qd = lnvS[t] * vb[t];
#pragma unroll
  for (int m = 32; m >= 1; m >>= 1) qd += __shfl_xor(qd, m);
  __syncthreads();
  if ((t & 63) == 0) red[wv] = qd;
  __syncthreads();
  if (t == 0) stage[bk * 8 + 5] = red[0] + red[1] + red[2] + red[3];
}

// ---------------- finalize ----------------
__global__ __launch_bounds__(256) void k_finalize(
    const float* __restrict__ sf, const float* __restrict__ attn0,
    const float* __restrict__ pos, const float* __restrict__ scl,
    const float* __restrict__ stage, float* __restrict__ out) {
  const int bk = blockIdx.x, t = threadIdx.x;
  out[bk * 260 + t] = sf[bk * 260 + t];
  if (t == 0) {
    const float Sa = stage[bk * 8 + 0];
    const float G0 = stage[bk * 8 + 1];
    const float G1 = stage[bk * 8 + 2];
    const float Q0 = stage[bk * 8 + 3];
    const float Q1 = stage[bk * 8 + 4];
    const float W = Sa + (float)NN * EPSA;
    const float sc0 = sqrtf(fmaxf(Q0 - 2.0f * G0 * G0 + G0 * G0 * W, 0.f));
    const float sc1 = sqrtf(fmaxf(Q1 - 2.0f * G1 * G1 + G1 * G1 * W, 0.f));
    out[bk * 260 + 256] = G0;
    out[bk * 260 + 257] = G1;
    out[bk * 260 + 258] = fminf(fmaxf(sc0, 1e-3f), 2.0f);
    out[bk * 260 + 259] = fminf(fmaxf(sc1, 1e-3f), 2.0f);
  }
  const float p0 = pos[bk * 2 + 0], p1 = pos[bk * 2 + 1];
  const float s0 = scl[bk * 2 + 0] * 5.0f, s1 = scl[bk * 2 + 1] * 5.0f;
#pragma unroll
  for (int i = 0; i < 4; i++) {
    const int n = t + 256 * i;
    out[16640 + bk * NN + n] = attn0[(size_t)bk * NN + n];
    const float gx = -1.0f + GSTEP * (float)(n >> 5);
    const float gy = -1.0f + GSTEP * (float)(n & 31);
    float2 v;
    v.x = (gx - p0) / s0;
    v.y = (gy - p1) / s1;
    *(float2*)(out + 16640 + 65536 + ((size_t)bk * NN + n) * 2) = v;
  }
}

extern "C" void kernel_launch(void* const* d_in, const int* in_sizes, int n_in,
                              void* d_out, int out_size, void* d_ws, size_t ws_size,
                              hipStream_t stream) {
  const float* inputs   = (const float*)d_in[0];
  const float* cond     = (const float*)d_in[1];
  const float* ni_g     = (const float*)d_in[2];
  const float* ni_b     = (const float*)d_in[3];
  const float* ns_g     = (const float*)d_in[4];
  const float* ns_b     = (const float*)d_in[5];
  const float* wq       = (const float*)d_in[6];
  const float* wk       = (const float*)d_in[7];
  const float* wv       = (const float*)d_in[8];
  const float* gp_w     = (const float*)d_in[9];
  const float* gp_b     = (const float*)d_in[10];
  const float* ge_ln_g  = (const float*)d_in[11];
  const float* ge_ln_b  = (const float*)d_in[12];
  const float* ge_w1    = (const float*)d_in[13];
  const float* ge_b1    = (const float*)d_in[14];
  const float* ge_w2    = (const float*)d_in[15];
  const float* ge_b2    = (const float*)d_in[16];
  const float* gru_wih  = (const float*)d_in[17];
  const float* gru_whh  = (const float*)d_in[18];
  const float* gru_bih  = (const float*)d_in[19];
  const float* gru_bhh  = (const float*)d_in[20];

  float* ws   = (float*)d_ws;
  float* php  = ws;                  // 64*8*8*512 = 2097152
  float* sf   = php + 2097152;       // 64*260
  float* w2qb = sf + 16640;          // 64*512
  float* posb = w2qb + 32768;        // 64*2 (padded)
  float* sclb = posb + 128;          // 64*2 (padded)
  float* dotsb = sclb + 128;         // 64*1024
  float* at0  = dotsb + 65536;       // 64*1024
  float* stag = at0 + 65536;         // 64*8
  float* bxb  = stag + 512;          // 768
  float* vbb  = bxb + 768;           // 256
  float* momk = vbb + 256;           // 8192*4
  float* momv = momk + 32768;        // 8192*4
  float* vecs = momv + 32768;        // 2560 (4*512 vecs + 5 scalars)
  short* w1T  = (short*)(vecs + 2560);    // 512*256 bf16 (packed fragment order)
  short* wkT  = w1T + 131072;             // 256*256 bf16 (packed fragment order)
  short* wvT  = wkT + 65536;              // 256*256 bf16 (packed fragment order)
  short* whhp = wvT + 65536;              // 768*256 bf16 (packed GEMV layout)
  short* w2B  = whhp + 196608;            // 512*256 bf16
  short* WXTp = w2B + 131072;             // 768*512 bf16 (packed GEMV layout)
  short* MQp  = WXTp + 393216;            // 256*512 bf16 (packed GEMV layout)
  short* KWk  = MQp + 131072;             // 8192*512 bf16
  short* KWv  = KWk + 4194304;            // 8192*512 bf16

  float* out = (float*)d_out;

  k_cvt_all<<<673, 256, 0, stream>>>(ge_w1, ge_w2, wk, wv, gru_wih, gru_whh, wq,
                                     ge_b2, gp_w, ge_ln_g, ge_ln_b, ge_b1,
                                     w1T, wkT, wvT, whhp, w2B, bxb, vbb, vecs);
  k_mm<<<dim3(12, 4, 2), 256, 0, stream>>>(gru_wih, wq, w2B, WXTp, MQp);
  k_kv_kw<<<dim3(128, 1, 2), 256, 0, stream>>>(inputs, ni_g, ni_b, wkT, wvT,
                                               gp_b, gp_w, ge_ln_g, w1T,
                                               KWk, KWv, momk, momv);
  k_slot0<<<NBK, 256, 0, stream>>>(sf, cond, ns_g, ns_b, MQp, vbb,
                                   w2qb, posb, sclb, stag);

  for (int s = 0; s < 3; s++) {
    k_iter<<<dim3(64, NB), 256, 0, stream>>>(KWk, KWv, momk, momv, vecs,
                                             posb, sclb, w2qb, stag, php);
    k_tail<<<NBK, 256, 0, stream>>>(php, sf, WXTp, whhp, bxb,
                                    gru_bih, gru_bhh, ns_g, ns_b, MQp, vbb,
                                    w2qb, posb, sclb, stag);
  }
  k_dots<<<dim3(128, NB, 2), 256, 0, stream>>>(KWk, momk, vecs, posb, sclb,
                                               w2qb, stag, dotsb);
  k_softmax_reduce<<<128, 64, 0, stream>>>(dotsb, at0, stag);

  k_finalize<<<NBK, 256, 0, stream>>>(sf, at0, posb, sclb, stag, out);
}

// Round 11
// 367.566 us; speedup vs baseline: 1.3514x; 1.3514x over previous
//
#include <hip/hip_runtime.h>
#include <math.h>

#define NB 8
#define NN 1024
#define NK 8
#define ND 256
#define ND2 512
#define NBK 64
#define EPSA 1e-8f
#define LNEPS 1e-5f
#define GSTEP (2.0f/31.0f)

using short8 = __attribute__((ext_vector_type(8))) short;
using short4v = __attribute__((ext_vector_type(4))) short;
using floatx4 = __attribute__((ext_vector_type(4))) float;

__device__ __forceinline__ short f2bf(float f) {
  unsigned u = __builtin_bit_cast(unsigned, f);
  u += 0x7fffu + ((u >> 16) & 1u);
  return (short)(u >> 16);
}
__device__ __forceinline__ float bf2f(short s) {
  unsigned u = ((unsigned)(unsigned short)s) << 16;
  return __builtin_bit_cast(float, u);
}

// ---------------- weight conversions + bias folds + rank-2 vectors + scalars ----------------
__global__ __launch_bounds__(256) void k_cvt_all(
    const float* __restrict__ w1, const float* __restrict__ w2,
    const float* __restrict__ wk, const float* __restrict__ wv,
    const float* __restrict__ wih, const float* __restrict__ whh,
    const float* __restrict__ wq, const float* __restrict__ b2,
    const float* __restrict__ gpw, const float* __restrict__ lng,
    const float* __restrict__ lnb, const float* __restrict__ b1,
    short* __restrict__ w1T, short* __restrict__ wkT, short* __restrict__ wvT,
    short* __restrict__ whhp, short* __restrict__ w2B,
    float* __restrict__ bx, float* __restrict__ vb, float* __restrict__ vecs) {
  __shared__ float redS[4][32];
  const int blk = blockIdx.x;
  const int t = threadIdx.x;
  if (blk < 576) {
    const int id4 = blk * 256 + t;
    if (id4 < 32768) {
      const int i = id4 * 4;
      const int k = i >> 9, n0 = i & 511;
      const float4 v = *(const float4*)(w1 + (size_t)k * 512 + n0);
      const float vv[4] = {v.x, v.y, v.z, v.w};
#pragma unroll
      for (int q = 0; q < 4; q++) {
        const int n = n0 + q;
        const int dst = ((n >> 4) * 8 + (k >> 5)) * 512 + ((k >> 3) & 3) * 128 + (n & 15) * 8 + (k & 7);
        w1T[dst] = f2bf(vv[q]);
      }
    } else if (id4 < 49152) {
      const int i = (id4 - 32768) * 4;
      const int k = i >> 8, n0 = i & 255;
      const float4 v = *(const float4*)(wk + (size_t)k * 256 + n0);
      const float vv[4] = {v.x, v.y, v.z, v.w};
#pragma unroll
      for (int q = 0; q < 4; q++) {
        const int n = n0 + q;
        const int dst = ((n >> 4) * 8 + (k >> 5)) * 512 + ((k >> 3) & 3) * 128 + (n & 15) * 8 + (k & 7);
        wkT[dst] = f2bf(vv[q]);
      }
    } else if (id4 < 65536) {
      const int i = (id4 - 49152) * 4;
      const int k = i >> 8, n0 = i & 255;
      const float4 v = *(const float4*)(wv + (size_t)k * 256 + n0);
      const float vv[4] = {v.x, v.y, v.z, v.w};
#pragma unroll
      for (int q = 0; q < 4; q++) {
        const int n = n0 + q;
        const int dst = ((n >> 4) * 8 + (k >> 5)) * 512 + ((k >> 3) & 3) * 128 + (n & 15) * 8 + (k & 7);
        wvT[dst] = f2bf(vv[q]);
      }
    } else if (id4 < 114688) {
      const int i = (id4 - 65536) * 4;
      const int j = i >> 8, d0 = i & 255;
      const float4 v = *(const float4*)(whh + i);
      short4v pk = {f2bf(v.x), f2bf(v.y), f2bf(v.z), f2bf(v.w)};
      *(short4v*)&whhp[(size_t)((d0 >> 3) * 768 + j) * 8 + (d0 & 7)] = pk;
    } else {
      const int i = (id4 - 114688) * 4;
      const float4 v = *(const float4*)(w2 + i);
      short4v pk = {f2bf(v.x), f2bf(v.y), f2bf(v.z), f2bf(v.w)};
      *(short4v*)&w2B[i] = pk;
    }
  } else {
    const int fb = blk - 576;
    if (fb < 24) {
      const int o = t >> 3, sub = t & 7;
      const int j = fb * 32 + o;
      float p = 0.f;
#pragma unroll
      for (int q = 0; q < 8; q++) {
        const int d = sub * 32 + q * 4;
        const float4 wv4 = *(const float4*)(wih + (size_t)j * 256 + d);
        const float4 b4 = *(const float4*)(b2 + d);
        p += wv4.x * b4.x + wv4.y * b4.y + wv4.z * b4.z + wv4.w * b4.w;
      }
      p += __shfl_xor(p, 1); p += __shfl_xor(p, 2); p += __shfl_xor(p, 4);
      if (sub == 0) bx[j] = p;
    } else if (fb < 32) {
      const int o = t >> 3, sub = t & 7;
      const int e = (fb - 24) * 32 + o;
      float p = 0.f;
#pragma unroll
      for (int q = 0; q < 8; q++) {
        const int d = sub * 32 + q * 4;
        const float4 wv4 = *(const float4*)(wq + (size_t)e * 256 + d);
        const float4 b4 = *(const float4*)(b2 + d);
        p += wv4.x * b4.x + wv4.y * b4.y + wv4.z * b4.z + wv4.w * b4.w;
      }
      p += __shfl_xor(p, 1); p += __shfl_xor(p, 2); p += __shfl_xor(p, 4);
      if (sub == 0) vb[e] = p;
    } else if (fb < 96) {
      const int v = (fb - 32) >> 4;
      const int j0 = ((fb - 32) & 15) * 32;
      const int sub = t >> 5, o = t & 31;
      const int j = j0 + o;
      float p = 0.f;
#pragma unroll 8
      for (int q = 0; q < 32; q++) {
        const int d = sub * 32 + q;
        float c;
        if (v == 0) c = gpw[d] * lng[d];
        else if (v == 1) c = gpw[256 + d] * lng[d];
        else if (v == 2) c = lng[d];
        else c = lnb[d];
        p = fmaf(c, w1[(size_t)d * 512 + j], p);
      }
      p += __shfl_xor(p, 32);
      const int w = t >> 6;
      if ((t & 32) == 0) redS[w][o] = p;
      __syncthreads();
      if (t < 32) {
        float s = redS[0][t] + redS[1][t] + redS[2][t] + redS[3][t];
        if (v == 3) s += b1[j0 + t];
        vecs[v * 512 + j0 + t] = s;
      }
    } else {
      const float wa = gpw[t], wb = gpw[256 + t];
      float v0 = wa, v1 = wb, v2 = wa * wa, v3 = wb * wb, v4 = wa * wb;
#pragma unroll
      for (int m = 32; m >= 1; m >>= 1) {
        v0 += __shfl_xor(v0, m); v1 += __shfl_xor(v1, m); v2 += __shfl_xor(v2, m);
        v3 += __shfl_xor(v3, m); v4 += __shfl_xor(v4, m);
      }
      const int wv2 = t >> 6;
      if ((t & 63) == 0) {
        redS[wv2][0] = v0; redS[wv2][1] = v1; redS[wv2][2] = v2;
        redS[wv2][3] = v3; redS[wv2][4] = v4;
      }
      __syncthreads();
      if (t < 5)
        vecs[2048 + t] = (redS[0][t] + redS[1][t] + redS[2][t] + redS[3][t]) * (1.0f / 256.0f);
    }
  }
}

// ---------------- precompute WXTp/MQp (packed GEMV layouts) via MFMA ----------------
__global__ __launch_bounds__(256, 2) void k_mm(
    const float* __restrict__ wih, const float* __restrict__ wq,
    const short* __restrict__ w2B,
    short* __restrict__ WXTp, short* __restrict__ MQp) {
  const int z = blockIdx.z;
  if (z == 1 && blockIdx.x >= 4) return;
  const float* __restrict__ A = z ? wq : wih;
  __shared__ __align__(16) short As[64 * 264];
  const int row0 = blockIdx.x * 64;
  const int col0 = blockIdx.y * 128;
  const int t = threadIdx.x;
  const int wave = t >> 6, lane = t & 63, l15 = lane & 15, quad = lane >> 4;
  {
    const int r = t >> 2, sub = t & 3;
    const float* ar = A + (size_t)(row0 + r) * 256;
#pragma unroll
    for (int ii = 0; ii < 16; ii++) {
      const int d = sub * 4 + ii * 16;
      const float4 v = *(const float4*)(ar + d);
      short4v pk = {f2bf(v.x), f2bf(v.y), f2bf(v.z), f2bf(v.w)};
      *(short4v*)&As[r * 264 + d] = pk;
    }
  }
  __syncthreads();
  const short* wp = w2B + (size_t)(col0 + wave * 32 + l15) * 256 + quad * 8;
  floatx4 acc[4][2];
#pragma unroll
  for (int mt = 0; mt < 4; mt++)
#pragma unroll
    for (int nt = 0; nt < 2; nt++) acc[mt][nt] = (floatx4){0.f, 0.f, 0.f, 0.f};
#pragma unroll
  for (int kk = 0; kk < 8; kk++) {
    short8 af[4];
#pragma unroll
    for (int mt = 0; mt < 4; mt++)
      af[mt] = *(const short8*)&As[(mt * 16 + l15) * 264 + kk * 32 + quad * 8];
    short8 bf[2];
#pragma unroll
    for (int nt = 0; nt < 2; nt++)
      bf[nt] = *(const short8*)(wp + nt * 16 * 256 + kk * 32);
#pragma unroll
    for (int mt = 0; mt < 4; mt++)
#pragma unroll
      for (int nt = 0; nt < 2; nt++)
        acc[mt][nt] = __builtin_amdgcn_mfma_f32_16x16x32_bf16(af[mt], bf[nt], acc[mt][nt], 0, 0, 0);
  }
#pragma unroll
  for (int mt = 0; mt < 4; mt++)
#pragma unroll
    for (int nt = 0; nt < 2; nt++)
#pragma unroll
      for (int j = 0; j < 4; j++) {
        const int row = row0 + mt * 16 + quad * 4 + j;
        const int col = col0 + wave * 32 + nt * 16 + l15;
        const short val = f2bf(acc[mt][nt][j]);
        if (z) MQp[(size_t)((row >> 3) * 512 + col) * 8 + (row & 7)] = val;
        else   WXTp[(size_t)((col >> 3) * 768 + row) * 8 + (col & 7)] = val;
      }
}

// ---------------- k_kv_kw: fused LN->kv MFMA->(+gpb)*g + moments -> @W1 MFMA -> KW ----------------
__global__ __launch_bounds__(256, 2) void k_kv_kw(
    const float* __restrict__ inp,
    const float* __restrict__ nig, const float* __restrict__ nib,
    const short* __restrict__ wkT, const short* __restrict__ wvT,
    const float* __restrict__ gpb, const float* __restrict__ gpw,
    const float* __restrict__ lng,
    const short* __restrict__ w1T,
    short* __restrict__ KWk, short* __restrict__ KWv,
    float* __restrict__ momk, float* __restrict__ momv) {
  __shared__ __align__(16) short tln[64 * 264];
  __shared__ float momS[64][4][4];
  const short* __restrict__ WT = blockIdx.z ? wvT : wkT;
  short* __restrict__ KW = blockIdx.z ? KWv : KWk;
  float* __restrict__ mom = blockIdx.z ? momv : momk;
  const int row0 = blockIdx.x * 64;
  const int t = threadIdx.x;
  const int wave = t >> 6, lane = t & 63, l15 = lane & 15, quad = lane >> 4;
  {
    const int r = t >> 2, sub = t & 3;
    const float* xr = inp + (size_t)(row0 + r) * ND;
    float tv[64];
    float sum = 0.f, ssq = 0.f;
#pragma unroll
    for (int ii = 0; ii < 16; ii++) {
      const int d = sub * 4 + ii * 16;
      const float4 xv = *(const float4*)(xr + d);
      tv[ii * 4 + 0] = xv.x; sum += xv.x; ssq += xv.x * xv.x;
      tv[ii * 4 + 1] = xv.y; sum += xv.y; ssq += xv.y * xv.y;
      tv[ii * 4 + 2] = xv.z; sum += xv.z; ssq += xv.z * xv.z;
      tv[ii * 4 + 3] = xv.w; sum += xv.w; ssq += xv.w * xv.w;
    }
    sum += __shfl_xor(sum, 1); ssq += __shfl_xor(ssq, 1);
    sum += __shfl_xor(sum, 2); ssq += __shfl_xor(ssq, 2);
    const float mean = sum * (1.0f / ND);
    const float var = ssq * (1.0f / ND) - mean * mean;
    const float rstd = rsqrtf(var + LNEPS);
#pragma unroll
    for (int ii = 0; ii < 16; ii++) {
      const int d = sub * 4 + ii * 16;
      const float4 gg = *(const float4*)(nig + d);
      const float4 bb = *(const float4*)(nib + d);
      short4v pk;
      pk.x = f2bf((tv[ii * 4 + 0] - mean) * rstd * gg.x + bb.x);
      pk.y = f2bf((tv[ii * 4 + 1] - mean) * rstd * gg.y + bb.y);
      pk.z = f2bf((tv[ii * 4 + 2] - mean) * rstd * gg.z + bb.z);
      pk.w = f2bf((tv[ii * 4 + 3] - mean) * rstd * gg.w + bb.w);
      *(short4v*)&tln[r * 264 + d] = pk;
    }
  }
  __syncthreads();
  floatx4 acc[4][4];
#pragma unroll
  for (int mt = 0; mt < 4; mt++)
#pragma unroll
    for (int nt = 0; nt < 4; nt++) acc[mt][nt] = (floatx4){0.f, 0.f, 0.f, 0.f};
  {
    const short* wp = WT + (size_t)(wave * 32) * 512 + (size_t)lane * 8;
#pragma unroll
    for (int kk = 0; kk < 8; kk++) {
      short8 af[4];
#pragma unroll
      for (int mt = 0; mt < 4; mt++)
        af[mt] = *(const short8*)&tln[(mt * 16 + l15) * 264 + kk * 32 + quad * 8];
      short8 bf[4];
#pragma unroll
      for (int nt = 0; nt < 4; nt++)
        bf[nt] = *(const short8*)(wp + (nt * 8 + kk) * 512);
#pragma unroll
      for (int mt = 0; mt < 4; mt++)
#pragma unroll
        for (int nt = 0; nt < 4; nt++)
          acc[mt][nt] = __builtin_amdgcn_mfma_f32_16x16x32_bf16(af[mt], bf[nt], acc[mt][nt], 0, 0, 0);
    }
  }
  __syncthreads();
  {
    float waL[4], wbL[4], ggL[4], pbL[4];
#pragma unroll
    for (int nt = 0; nt < 4; nt++) {
      const int c = wave * 64 + nt * 16 + l15;
      waL[nt] = gpw[c]; wbL[nt] = gpw[256 + c];
      ggL[nt] = lng[c]; pbL[nt] = gpb[c];
    }
#pragma unroll
    for (int mt = 0; mt < 4; mt++)
#pragma unroll
      for (int j = 0; j < 4; j++) {
        const int row = mt * 16 + quad * 4 + j;
        float su = 0.f, sq = 0.f, sa = 0.f, sb = 0.f;
#pragma unroll
        for (int nt = 0; nt < 4; nt++) {
          const float u = acc[mt][nt][j] + pbL[nt];
          su += u; sq += u * u; sa += u * waL[nt]; sb += u * wbL[nt];
          tln[row * 264 + wave * 64 + nt * 16 + l15] = f2bf(u * ggL[nt]);
        }
        su += __shfl_xor(su, 1); sq += __shfl_xor(sq, 1);
        sa += __shfl_xor(sa, 1); sb += __shfl_xor(sb, 1);
        su += __shfl_xor(su, 2); sq += __shfl_xor(sq, 2);
        sa += __shfl_xor(sa, 2); sb += __shfl_xor(sb, 2);
        su += __shfl_xor(su, 4); sq += __shfl_xor(sq, 4);
        sa += __shfl_xor(sa, 4); sb += __shfl_xor(sb, 4);
        su += __shfl_xor(su, 8); sq += __shfl_xor(sq, 8);
        sa += __shfl_xor(sa, 8); sb += __shfl_xor(sb, 8);
        if (l15 == 0) {
          momS[row][wave][0] = su; momS[row][wave][1] = sq;
          momS[row][wave][2] = sa; momS[row][wave][3] = sb;
        }
      }
  }
  __syncthreads();
  if (t < 64) {
    const float m0 = momS[t][0][0] + momS[t][1][0] + momS[t][2][0] + momS[t][3][0];
    const float m1 = momS[t][0][1] + momS[t][1][1] + momS[t][2][1] + momS[t][3][1];
    const float m2 = momS[t][0][2] + momS[t][1][2] + momS[t][2][2] + momS[t][3][2];
    const float m3 = momS[t][0][3] + momS[t][1][3] + momS[t][2][3] + momS[t][3][3];
    float* mp = mom + (size_t)(row0 + t) * 4;
    mp[0] = m0 * (1.0f / ND); mp[1] = m1 * (1.0f / ND);
    mp[2] = m2 * (1.0f / ND); mp[3] = m3 * (1.0f / ND);
  }
  floatx4 acc2[4][8];
#pragma unroll
  for (int mt = 0; mt < 4; mt++)
#pragma unroll
    for (int nt = 0; nt < 8; nt++) acc2[mt][nt] = (floatx4){0.f, 0.f, 0.f, 0.f};
  const short* w1p = w1T + (size_t)(wave * 64) * 512 + (size_t)lane * 8;
#pragma unroll
  for (int kk = 0; kk < 8; kk++) {
    short8 af[4];
#pragma unroll
    for (int mt = 0; mt < 4; mt++)
      af[mt] = *(const short8*)&tln[(mt * 16 + l15) * 264 + kk * 32 + quad * 8];
    short8 bf[8];
#pragma unroll
    for (int nt = 0; nt < 8; nt++)
      bf[nt] = *(const short8*)(w1p + (nt * 8 + kk) * 512);
#pragma unroll
    for (int mt = 0; mt < 4; mt++)
#pragma unroll
      for (int nt = 0; nt < 8; nt++)
        acc2[mt][nt] = __builtin_amdgcn_mfma_f32_16x16x32_bf16(af[mt], bf[nt], acc2[mt][nt], 0, 0, 0);
  }
#pragma unroll
  for (int mt = 0; mt < 4; mt++)
#pragma unroll
    for (int nt = 0; nt < 8; nt++)
#pragma unroll
      for (int j = 0; j < 4; j++)
        KW[(size_t)(row0 + mt * 16 + quad * 4 + j) * 512 + wave * 128 + nt * 16 + l15] =
            f2bf(acc2[mt][nt][j]);
}

// ---------------- k_dotsm: fused dots(8 slots) + softmax + moments -> attn0 + stage ----------------
// grid (128, NB): 8 rows per block, wave handles 2 rows. No ph phase (low VGPR).
__global__ __launch_bounds__(256) void k_dotsm(
    const short* __restrict__ KWk, const float* __restrict__ momk,
    const float* __restrict__ vecs,
    const float* __restrict__ pos, const float* __restrict__ scl,
    const float* __restrict__ w2q, float* __restrict__ stage,
    float* __restrict__ attn0) {
  const int b = blockIdx.y, nt = blockIdx.x;
  const int t = threadIdx.x, wave = t >> 6, lane = t & 63;
  __shared__ float w2qS[8 * 512];
  __shared__ float momRed[4][40];
#pragma unroll
  for (int q = 0; q < 16; q++)
    w2qS[q * 256 + t] = w2q[(size_t)b * 4096 + q * 256 + t];
  __syncthreads();
  float AWv[8], BWv[8], GWv[8], bWv[8];
#pragma unroll
  for (int e = 0; e < 8; e++) {
    const int j = e * 64 + lane;
    AWv[e] = vecs[j]; BWv[e] = vecs[512 + j];
    GWv[e] = vecs[1024 + j]; bWv[e] = vecs[1536 + j];
  }
  const float mwa = vecs[2048], mwb = vecs[2049];
  const float ewa2 = vecs[2050], ewb2 = vecs[2051], ewab = vecs[2052];
  float p0[8], p1[8], si0[8], si1[8], qb2[8];
#pragma unroll
  for (int k = 0; k < 8; k++) {
    const int bk = b * 8 + k;
    p0[k] = pos[bk * 2]; p1[k] = pos[bk * 2 + 1];
    si0[k] = 1.0f / (scl[bk * 2] * 5.0f);
    si1[k] = 1.0f / (scl[bk * 2 + 1] * 5.0f);
    qb2[k] = stage[bk * 8 + 5];
  }
  float msum = 0.f;
  const int mk = lane / 5, mc = lane - mk * 5;  // lane<40: owns moment (mk, mc)
#pragma unroll
  for (int i = 0; i < 2; i++) {
    const int n = nt * 8 + wave * 2 + i;
    const int row = b * NN + n;
    const float gx = -1.0f + GSTEP * (float)(n >> 5);
    const float gy = -1.0f + GSTEP * (float)(n & 31);
    float KWr[8];
#pragma unroll
    for (int e = 0; e < 8; e++) KWr[e] = bf2f(KWk[(size_t)row * 512 + e * 64 + lane]);
    const float mu = momk[row * 4 + 0], qm = momk[row * 4 + 1];
    const float ca = momk[row * 4 + 2], cb = momk[row * 4 + 3];
    float dk[8];
#pragma unroll
    for (int k = 0; k < 8; k++) {
      const float rg0 = (gx - p0[k]) * si0[k];
      const float rg1 = (gy - p1[k]) * si1[k];
      const float mean = mu + rg0 * mwa + rg1 * mwb;
      const float ey2 = qm + rg0 * rg0 * ewa2 + rg1 * rg1 * ewb2 +
                        2.0f * (rg0 * ca + rg1 * cb + rg0 * rg1 * ewab);
      const float rstd = rsqrtf(ey2 - mean * mean + LNEPS);
      float d = 0.f;
#pragma unroll
      for (int e = 0; e < 8; e++) {
        float tt = KWr[e];
        tt = fmaf(rg0, AWv[e], tt);
        tt = fmaf(rg1, BWv[e], tt);
        tt = fmaf(-mean, GWv[e], tt);
        const float h = fmaf(rstd, tt, bWv[e]);
        d = fmaf(fmaxf(h, 0.f), w2qS[k * 512 + e * 64 + lane], d);
      }
      d += __shfl_xor(d, 1); d += __shfl_xor(d, 2); d += __shfl_xor(d, 4);
      d += __shfl_xor(d, 8); d += __shfl_xor(d, 16); d += __shfl_xor(d, 32);
      dk[k] = (d + qb2[k]) * 0.0625f;
    }
    // softmax over the 8 slots (wave-uniform after butterfly)
    float mx = dk[0];
#pragma unroll
    for (int k = 1; k < 8; k++) mx = fmaxf(mx, dk[k]);
    float s = 0.f;
#pragma unroll
    for (int k = 0; k < 8; k++) { dk[k] = expf(dk[k] - mx); s += dk[k]; }
    const float inv = 1.0f / s;
#pragma unroll
    for (int k = 0; k < 8; k++) {
      dk[k] *= inv;
      if (lane == 0) attn0[(size_t)(b * 8 + k) * NN + n] = dk[k];
    }
    // moments (lane<40: one (k,c) each)
    if (lane < 40) {
      const float a = dk[mk];
      float mval;
      if (mc == 0) mval = a;
      else if (mc == 1) mval = a * gx;
      else if (mc == 2) mval = a * gy;
      else if (mc == 3) mval = (a + EPSA) * gx * gx;
      else mval = (a + EPSA) * gy * gy;
      msum += mval;
    }
  }
  if (lane < 40) momRed[wave][lane] = msum;
  __syncthreads();
  if (t < 40) {
    const float tot = momRed[0][t] + momRed[1][t] + momRed[2][t] + momRed[3][t];
    atomicAdd(&stage[(b * 8 + t / 5) * 8 + (t % 5)], tot);
  }
}

// ---------------- k_ph: attn-weighted relu(h1) accumulation -> 64 partials ----------------
// grid (64, 8, 2): 16 rows per block, wave 4 rows; z picks 4 of 8 slots.
__global__ __launch_bounds__(256) void k_ph(
    const short* __restrict__ KW, const float* __restrict__ mom,
    const float* __restrict__ vecs,
    const float* __restrict__ pos, const float* __restrict__ scl,
    const float* __restrict__ attn0, float* __restrict__ php) {
  const int b = blockIdx.y, nt = blockIdx.x, kk0 = blockIdx.z * 4;
  const int t = threadIdx.x, wave = t >> 6, lane = t & 63;
  __shared__ float phs[4 * 512];
  float AWv[8], BWv[8], GWv[8], bWv[8];
#pragma unroll
  for (int e = 0; e < 8; e++) {
    const int j = e * 64 + lane;
    AWv[e] = vecs[j]; BWv[e] = vecs[512 + j];
    GWv[e] = vecs[1024 + j]; bWv[e] = vecs[1536 + j];
  }
  const float mwa = vecs[2048], mwb = vecs[2049];
  const float ewa2 = vecs[2050], ewb2 = vecs[2051], ewab = vecs[2052];
  float p0[4], p1[4], si0[4], si1[4];
#pragma unroll
  for (int k = 0; k < 4; k++) {
    const int bk = b * 8 + kk0 + k;
    p0[k] = pos[bk * 2]; p1[k] = pos[bk * 2 + 1];
    si0[k] = 1.0f / (scl[bk * 2] * 5.0f);
    si1[k] = 1.0f / (scl[bk * 2 + 1] * 5.0f);
  }
  float acc[4][8];
#pragma unroll
  for (int k = 0; k < 4; k++)
#pragma unroll
    for (int e = 0; e < 8; e++) acc[k][e] = 0.f;
#pragma unroll
  for (int i = 0; i < 4; i++) {
    const int n = nt * 16 + wave * 4 + i;
    const int row = b * NN + n;
    float KWr[8];
#pragma unroll
    for (int e = 0; e < 8; e++) KWr[e] = bf2f(KW[(size_t)row * 512 + e * 64 + lane]);
    const float mu = mom[row * 4 + 0], qm = mom[row * 4 + 1];
    const float ca = mom[row * 4 + 2], cb = mom[row * 4 + 3];
    const float gx = -1.0f + GSTEP * (float)(n >> 5);
    const float gy = -1.0f + GSTEP * (float)(n & 31);
#pragma unroll
    for (int k = 0; k < 4; k++) {
      const float rg0 = (gx - p0[k]) * si0[k];
      const float rg1 = (gy - p1[k]) * si1[k];
      const float mean = mu + rg0 * mwa + rg1 * mwb;
      const float ey2 = qm + rg0 * rg0 * ewa2 + rg1 * rg1 * ewb2 +
                        2.0f * (rg0 * ca + rg1 * cb + rg0 * rg1 * ewab);
      const float rstd = rsqrtf(ey2 - mean * mean + LNEPS);
      const float aw = attn0[(size_t)(b * 8 + kk0 + k) * NN + n] + EPSA;
#pragma unroll
      for (int e = 0; e < 8; e++) {
        float tt = KWr[e];
        tt = fmaf(rg0, AWv[e], tt);
        tt = fmaf(rg1, BWv[e], tt);
        tt = fmaf(-mean, GWv[e], tt);
        const float h = fmaf(rstd, tt, bWv[e]);
        acc[k][e] = fmaf(aw, fmaxf(h, 0.f), acc[k][e]);
      }
    }
  }
#pragma unroll
  for (int w = 0; w < 4; w++) {
    if (wave == w) {
#pragma unroll
      for (int k = 0; k < 4; k++)
#pragma unroll
        for (int e = 0; e < 8; e++) {
          const int j = e * 64 + lane;
          if (w == 0) phs[k * 512 + j] = acc[k][e];
          else phs[k * 512 + j] += acc[k][e];
        }
    }
    __syncthreads();
  }
  float* dst = php + (size_t)(((nt * 8 + b) * 8) + kk0) * 512;
  const int base = t * 8;
  *(float4*)(dst + base) = *(const float4*)(phs + base);
  *(float4*)(dst + base + 4) = *(const float4*)(phs + base + 4);
}

// ---------------- k_tail: phred(64 partials) + gates GEMV + GRU + LN + w2q + qb2 ----------------
__global__ __launch_bounds__(256) void k_tail(
    const float* __restrict__ php, float* __restrict__ sf,
    const short* __restrict__ WXTp, const short* __restrict__ whhp,
    const float* __restrict__ bx,
    const float* __restrict__ bih, const float* __restrict__ bhh,
    const float* __restrict__ nsg, const float* __restrict__ nsb,
    const short* __restrict__ MQp, const float* __restrict__ vb,
    float* __restrict__ w2q, float* __restrict__ pos, float* __restrict__ scl,
    float* __restrict__ stage) {
  const int bk = blockIdx.x, t = threadIdx.x;
  const int b = bk >> 3, k = bk & 7;
  __shared__ float phv[512];
  __shared__ float sfv[256];
  __shared__ float lnvS[256];
  __shared__ float red[8];
  const int wv = t >> 6;
  sfv[t] = sf[bk * 260 + t];
  const float dn = 1.0f / (stage[bk * 8 + 0] + (float)NN * EPSA);
  float s0 = 0.f, s1 = 0.f;
#pragma unroll 8
  for (int p = 0; p < 64; p++) {
    const float* src = php + (size_t)((p * 8 + b) * 8 + k) * 512;
    s0 += src[t];
    s1 += src[t + 256];
  }
  phv[t] = s0 * dn;
  phv[t + 256] = s1 * dn;
  __syncthreads();
  float x0 = bx[t], x1 = bx[256 + t], x2 = bx[512 + t];
#pragma unroll 4
  for (int e8 = 0; e8 < 64; e8++) {
    const float4 pa = *(const float4*)&phv[e8 * 8];
    const float4 pb4 = *(const float4*)&phv[e8 * 8 + 4];
    const float pv[8] = {pa.x, pa.y, pa.z, pa.w, pb4.x, pb4.y, pb4.z, pb4.w};
    const short8 wr0 = *(const short8*)&WXTp[(size_t)(e8 * 768 + t) * 8];
    const short8 wr1 = *(const short8*)&WXTp[(size_t)(e8 * 768 + 256 + t) * 8];
    const short8 wr2 = *(const short8*)&WXTp[(size_t)(e8 * 768 + 512 + t) * 8];
#pragma unroll
    for (int r = 0; r < 8; r++) {
      x0 = fmaf(pv[r], bf2f(wr0[r]), x0);
      x1 = fmaf(pv[r], bf2f(wr1[r]), x1);
      x2 = fmaf(pv[r], bf2f(wr2[r]), x2);
    }
  }
  float h0 = 0.f, h1v = 0.f, h2 = 0.f;
#pragma unroll 4
  for (int d8 = 0; d8 < 32; d8++) {
    const float4 sa = *(const float4*)&sfv[d8 * 8];
    const float4 sb4 = *(const float4*)&sfv[d8 * 8 + 4];
    const float sv[8] = {sa.x, sa.y, sa.z, sa.w, sb4.x, sb4.y, sb4.z, sb4.w};
    const short8 hr0 = *(const short8*)&whhp[(size_t)(d8 * 768 + t) * 8];
    const short8 hr1 = *(const short8*)&whhp[(size_t)(d8 * 768 + 256 + t) * 8];
    const short8 hr2 = *(const short8*)&whhp[(size_t)(d8 * 768 + 512 + t) * 8];
#pragma unroll
    for (int r = 0; r < 8; r++) {
      h0 = fmaf(sv[r], bf2f(hr0[r]), h0);
      h1v = fmaf(sv[r], bf2f(hr1[r]), h1v);
      h2 = fmaf(sv[r], bf2f(hr2[r]), h2);
    }
  }
  const float r = 1.0f / (1.0f + expf(-(x0 + bih[t] + h0 + bhh[t])));
  const float z = 1.0f / (1.0f + expf(-(x1 + bih[256 + t] + h1v + bhh[256 + t])));
  const float nw = tanhf(x2 + bih[512 + t] + r * (h2 + bhh[512 + t]));
  const float ns = (1.0f - z) * nw + z * sfv[t];
  sf[bk * 260 + t] = ns;
  float s2 = ns, ss = ns * ns;
#pragma unroll
  for (int m = 32; m >= 1; m >>= 1) { s2 += __shfl_xor(s2, m); ss += __shfl_xor(ss, m); }
  if ((t & 63) == 0) { red[wv] = s2; red[4 + wv] = ss; }
  __syncthreads();
  const float S = red[0] + red[1] + red[2] + red[3];
  const float SS = red[4] + red[5] + red[6] + red[7];
  const float mean = S * (1.0f / ND);
  const float var = SS * (1.0f / ND) - mean * mean;
  const float rstd = rsqrtf(var + LNEPS);
  const float lnv = (ns - mean) * rstd * nsg[t] + nsb[t];
  lnvS[t] = lnv;
  if (t == 0) {
    const float Sa = stage[bk * 8 + 0];
    const float G0 = stage[bk * 8 + 1];
    const float G1 = stage[bk * 8 + 2];
    const float Q0 = stage[bk * 8 + 3];
    const float Q1 = stage[bk * 8 + 4];
    const float W = Sa + (float)NN * EPSA;
    const float sc0 = sqrtf(fmaxf(Q0 - 2.0f * G0 * G0 + G0 * G0 * W, 0.f));
    const float sc1 = sqrtf(fmaxf(Q1 - 2.0f * G1 * G1 + G1 * G1 * W, 0.f));
    const float sc0c = fminf(fmaxf(sc0, 1e-3f), 2.0f);
    const float sc1c = fminf(fmaxf(sc1, 1e-3f), 2.0f);
    sf[bk * 260 + 256] = G0;
    sf[bk * 260 + 257] = G1;
    sf[bk * 260 + 258] = sc0c;
    sf[bk * 260 + 259] = sc1c;
    pos[bk * 2 + 0] = fminf(fmaxf(G0, -1.0f), 1.0f);
    pos[bk * 2 + 1] = fminf(fmaxf(G1, -1.0f), 1.0f);
    scl[bk * 2 + 0] = sc0c;
    scl[bk * 2 + 1] = sc1c;
  }
  __syncthreads();
  if (t < 5) stage[bk * 8 + t] = 0.f;
  float w0 = 0.f, w1v = 0.f;
#pragma unroll 4
  for (int e8 = 0; e8 < 32; e8++) {
    const float4 la = *(const float4*)&lnvS[e8 * 8];
    const float4 lb = *(const float4*)&lnvS[e8 * 8 + 4];
    const float lv[8] = {la.x, la.y, la.z, la.w, lb.x, lb.y, lb.z, lb.w};
    const short8 m0 = *(const short8*)&MQp[(size_t)(e8 * 512 + t) * 8];
    const short8 m1 = *(const short8*)&MQp[(size_t)(e8 * 512 + 256 + t) * 8];
#pragma unroll
    for (int rr = 0; rr < 8; rr++) {
      w0 = fmaf(lv[rr], bf2f(m0[rr]), w0);
      w1v = fmaf(lv[rr], bf2f(m1[rr]), w1v);
    }
  }
  w2q[bk * 512 + t] = w0;
  w2q[bk * 512 + 256 + t] = w1v;
  float qd = lnvS[t] * vb[t];
#pragma unroll
  for (int m = 32; m >= 1; m >>= 1) qd += __shfl_xor(qd, m);
  __syncthreads();
  if ((t & 63) == 0) red[wv] = qd;
  __syncthreads();
  if (t == 0) stage[bk * 8 + 5] = red[0] + red[1] + red[2] + red[3];
}

// ---------------- k_slot0: iteration-0 slot init (no GRU) ----------------
__global__ __launch_bounds__(256) void k_slot0(
    float* __restrict__ sf, const float* __restrict__ cond,
    const float* __restrict__ nsg, const float* __restrict__ nsb,
    const short* __restrict__ MQp, const float* __restrict__ vb,
    float* __restrict__ w2q, float* __restrict__ pos, float* __restrict__ scl,
    float* __restrict__ stage) {
  const int bk = blockIdx.x, t = threadIdx.x;
  __shared__ float lnvS[256];
  __shared__ float red[8];
  const int wv = t >> 6;
  const float ns = cond[bk * 260 + t];
  sf[bk * 260 + t] = ns;
  if (t < 4) sf[bk * 260 + 256 + t] = cond[bk * 260 + 256 + t];
  float s2 = ns, ss = ns * ns;
#pragma unroll
  for (int m = 32; m >= 1; m >>= 1) { s2 += __shfl_xor(s2, m); ss += __shfl_xor(ss, m); }
  if ((t & 63) == 0) { red[wv] = s2; red[4 + wv] = ss; }
  __syncthreads();
  const float S = red[0] + red[1] + red[2] + red[3];
  const float SS = red[4] + red[5] + red[6] + red[7];
  const float mean = S * (1.0f / ND);
  const float var = SS * (1.0f / ND) - mean * mean;
  const float rstd = rsqrtf(var + LNEPS);
  const float lnv = (ns - mean) * rstd * nsg[t] + nsb[t];
  lnvS[t] = lnv;
  if (t < 2) {
    const float p = cond[bk * 260 + 256 + t];
    pos[bk * 2 + t] = fminf(fmaxf(p, -1.0f), 1.0f);
    const float sc = cond[bk * 260 + 258 + t];
    scl[bk * 2 + t] = fminf(fmaxf(sc, 1e-3f), 2.0f);
  }
  __syncthreads();
  if (t < 5) stage[bk * 8 + t] = 0.f;
  float w0 = 0.f, w1v = 0.f;
#pragma unroll 4
  for (int e8 = 0; e8 < 32; e8++) {
    const float4 la = *(const float4*)&lnvS[e8 * 8];
    const float4 lb = *(const float4*)&lnvS[e8 * 8 + 4];
    const float lv[8] = {la.x, la.y, la.z, la.w, lb.x, lb.y, lb.z, lb.w};
    const short8 m0 = *(const short8*)&MQp[(size_t)(e8 * 512 + t) * 8];
    const short8 m1 = *(const short8*)&MQp[(size_t)(e8 * 512 + 256 + t) * 8];
#pragma unroll
    for (int rr = 0; rr < 8; rr++) {
      w0 = fmaf(lv[rr], bf2f(m0[rr]), w0);
      w1v = fmaf(lv[rr], bf2f(m1[rr]), w1v);
    }
  }
  w2q[bk * 512 + t] = w0;
  w2q[bk * 512 + 256 + t] = w1v;
  float qd = lnvS[t] * vb[t];
#pragma unroll
  for (int m = 32; m >= 1; m >>= 1) qd += __shfl_xor(qd, m);
  __syncthreads();
  if ((t & 63) == 0) red[wv] = qd;
  __syncthreads();
  if (t == 0) stage[bk * 8 + 5] = red[0] + red[1] + red[2] + red[3];
}

// ---------------- finalize ----------------
__global__ __launch_bounds__(256) void k_finalize(
    const float* __restrict__ sf, const float* __restrict__ attn0,
    const float* __restrict__ pos, const float* __restrict__ scl,
    const float* __restrict__ stage, float* __restrict__ out) {
  const int bk = blockIdx.x, t = threadIdx.x;
  out[bk * 260 + t] = sf[bk * 260 + t];
  if (t == 0) {
    const float Sa = stage[bk * 8 + 0];
    const float G0 = stage[bk * 8 + 1];
    const float G1 = stage[bk * 8 + 2];
    const float Q0 = stage[bk * 8 + 3];
    const float Q1 = stage[bk * 8 + 4];
    const float W = Sa + (float)NN * EPSA;
    const float sc0 = sqrtf(fmaxf(Q0 - 2.0f * G0 * G0 + G0 * G0 * W, 0.f));
    const float sc1 = sqrtf(fmaxf(Q1 - 2.0f * G1 * G1 + G1 * G1 * W, 0.f));
    out[bk * 260 + 256] = G0;
    out[bk * 260 + 257] = G1;
    out[bk * 260 + 258] = fminf(fmaxf(sc0, 1e-3f), 2.0f);
    out[bk * 260 + 259] = fminf(fmaxf(sc1, 1e-3f), 2.0f);
  }
  const float p0 = pos[bk * 2 + 0], p1 = pos[bk * 2 + 1];
  const float s0 = scl[bk * 2 + 0] * 5.0f, s1 = scl[bk * 2 + 1] * 5.0f;
#pragma unroll
  for (int i = 0; i < 4; i++) {
    const int n = t + 256 * i;
    out[16640 + bk * NN + n] = attn0[(size_t)bk * NN + n];
    const float gx = -1.0f + GSTEP * (float)(n >> 5);
    const float gy = -1.0f + GSTEP * (float)(n & 31);
    float2 v;
    v.x = (gx - p0) / s0;
    v.y = (gy - p1) / s1;
    *(float2*)(out + 16640 + 65536 + ((size_t)bk * NN + n) * 2) = v;
  }
}

extern "C" void kernel_launch(void* const* d_in, const int* in_sizes, int n_in,
                              void* d_out, int out_size, void* d_ws, size_t ws_size,
                              hipStream_t stream) {
  const float* inputs   = (const float*)d_in[0];
  const float* cond     = (const float*)d_in[1];
  const float* ni_g     = (const float*)d_in[2];
  const float* ni_b     = (const float*)d_in[3];
  const float* ns_g     = (const float*)d_in[4];
  const float* ns_b     = (const float*)d_in[5];
  const float* wq       = (const float*)d_in[6];
  const float* wk       = (const float*)d_in[7];
  const float* wv       = (const float*)d_in[8];
  const float* gp_w     = (const float*)d_in[9];
  const float* gp_b     = (const float*)d_in[10];
  const float* ge_ln_g  = (const float*)d_in[11];
  const float* ge_ln_b  = (const float*)d_in[12];
  const float* ge_w1    = (const float*)d_in[13];
  const float* ge_b1    = (const float*)d_in[14];
  const float* ge_w2    = (const float*)d_in[15];
  const float* ge_b2    = (const float*)d_in[16];
  const float* gru_wih  = (const float*)d_in[17];
  const float* gru_whh  = (const float*)d_in[18];
  const float* gru_bih  = (const float*)d_in[19];
  const float* gru_bhh  = (const float*)d_in[20];

  float* ws   = (float*)d_ws;
  float* php  = ws;                  // 64*8*8*512 = 2097152
  float* sf   = php + 2097152;       // 64*260
  float* w2qb = sf + 16640;          // 64*512
  float* posb = w2qb + 32768;        // 64*2 (padded)
  float* sclb = posb + 128;          // 64*2 (padded)
  float* dotsb = sclb + 128;         // 64*1024 (unused; layout keeper)
  float* at0  = dotsb + 65536;       // 64*1024
  float* stag = at0 + 65536;         // 64*8
  float* bxb  = stag + 512;          // 768
  float* vbb  = bxb + 768;           // 256
  float* momk = vbb + 256;           // 8192*4
  float* momv = momk + 32768;        // 8192*4
  float* vecs = momv + 32768;        // 2560 (4*512 vecs + 5 scalars)
  short* w1T  = (short*)(vecs + 2560);    // 512*256 bf16 (packed fragment order)
  short* wkT  = w1T + 131072;             // 256*256 bf16 (packed fragment order)
  short* wvT  = wkT + 65536;              // 256*256 bf16 (packed fragment order)
  short* whhp = wvT + 65536;              // 768*256 bf16 (packed GEMV layout)
  short* w2B  = whhp + 196608;            // 512*256 bf16
  short* WXTp = w2B + 131072;             // 768*512 bf16 (packed GEMV layout)
  short* MQp  = WXTp + 393216;            // 256*512 bf16 (packed GEMV layout)
  short* KWk  = MQp + 131072;             // 8192*512 bf16
  short* KWv  = KWk + 4194304;            // 8192*512 bf16

  float* out = (float*)d_out;

  k_cvt_all<<<673, 256, 0, stream>>>(ge_w1, ge_w2, wk, wv, gru_wih, gru_whh, wq,
                                     ge_b2, gp_w, ge_ln_g, ge_ln_b, ge_b1,
                                     w1T, wkT, wvT, whhp, w2B, bxb, vbb, vecs);
  k_mm<<<dim3(12, 4, 2), 256, 0, stream>>>(gru_wih, wq, w2B, WXTp, MQp);
  k_kv_kw<<<dim3(128, 1, 2), 256, 0, stream>>>(inputs, ni_g, ni_b, wkT, wvT,
                                               gp_b, gp_w, ge_ln_g, w1T,
                                               KWk, KWv, momk, momv);
  k_slot0<<<NBK, 256, 0, stream>>>(sf, cond, ns_g, ns_b, MQp, vbb,
                                   w2qb, posb, sclb, stag);

  for (int s = 0; s < 4; s++) {
    k_dotsm<<<dim3(128, NB), 256, 0, stream>>>(KWk, momk, vecs, posb, sclb,
                                               w2qb, stag, at0);
    if (s < 3) {
      k_ph<<<dim3(64, NB, 2), 256, 0, stream>>>(KWv, momv, vecs, posb, sclb,
                                                at0, php);
      k_tail<<<NBK, 256, 0, stream>>>(php, sf, WXTp, whhp, bxb,
                                      gru_bih, gru_bhh, ns_g, ns_b, MQp, vbb,
                                      w2qb, posb, sclb, stag);
    }
  }

  k_finalize<<<NBK, 256, 0, stream>>>(sf, at0, posb, sclb, stag, out);
}